// Round 5
// baseline (967.381 us; speedup 1.0000x reference)
//
#include <hip/hip_runtime.h>
#include <hip/hip_bf16.h>
#include <math.h>

// Problem dims (compile-time)
constexpr int NB = 64;     // batch
constexpr int NT = 30;     // decode steps
constexpr int NS = 31;     // encoder positions
constexpr int NE = 128;    // embedding dim
constexpr int NU = 256;    // hidden
constexpr int NV = 32000;  // vocab
constexpr int NG = 4 * NU;    // 1024 (gates)

typedef unsigned short u16;
typedef __attribute__((ext_vector_type(8))) short bf16x8;
typedef __attribute__((ext_vector_type(4))) float f32x4;

__device__ __forceinline__ float sigmoidf_(float x) {
    return 1.0f / (1.0f + __expf(-x));
}

__device__ __forceinline__ u16 rne_bf16(float x) {
    unsigned u = __float_as_uint(x);
    unsigned r = u + 0x7fffu + ((u >> 16) & 1u);
    return (u16)(r >> 16);
}

// ---------------------------------------------------------------------------
// keys[b,s,v] = sum_u memory[b,s,u] * W_mem[u,v]
// ---------------------------------------------------------------------------
__global__ __launch_bounds__(256) void keys_kernel(
    const float* __restrict__ memory, const float* __restrict__ W_mem,
    float* __restrict__ keys) {
    const int row0 = blockIdx.x * 8;
    const int u = threadIdx.x;
    __shared__ float mS[8][NU];
#pragma unroll
    for (int r = 0; r < 8; ++r) mS[r][u] = memory[(row0 + r) * NU + u];
    __syncthreads();
    float acc[8] = {0, 0, 0, 0, 0, 0, 0, 0};
#pragma unroll 4
    for (int v = 0; v < NU; ++v) {
        float w = W_mem[v * NU + u];
#pragma unroll
        for (int r = 0; r < 8; ++r) acc[r] += mS[r][v] * w;
    }
#pragma unroll
    for (int r = 0; r < 8; ++r) keys[(row0 + r) * NU + u] = acc[r];
}

// ---------------------------------------------------------------------------
// Fused recurrent weights, written as 4 per-u-slice panels:
//   Wz[i][n] = W_attn[i][:] . W_k[128:384][n]  (+ W_r[i][n] if i<256)
// Panel layout: Wzp[qb][i][lc], lc = gate*64 + (u&63).
// ---------------------------------------------------------------------------
__global__ __launch_bounds__(256) void fuse_wz_kernel(
    const float* __restrict__ W_k,   // [384, NG]
    const float* __restrict__ W_r,   // [NU, NG]
    const float* __restrict__ W_a,   // [2*NU, NU]
    float* __restrict__ Wzp)         // [4][512][256]
{
    const int col = blockIdx.x * 256 + threadIdx.x;  // z-col n, 0..1023
    const int rb = blockIdx.y * 8;
    __shared__ float waS[8][NU];
#pragma unroll
    for (int r = 0; r < 8; ++r) waS[r][threadIdx.x] = W_a[(size_t)(rb + r) * NU + threadIdx.x];
    __syncthreads();
    float acc[8] = {};
#pragma unroll 4
    for (int j = 0; j < NU; ++j) {
        float w = W_k[(size_t)(NE + j) * NG + col];
#pragma unroll
        for (int r = 0; r < 8; ++r) acc[r] += waS[r][j] * w;
    }
    const int gate = col >> 8, u = col & 255;
    const int qb = u >> 6, lc = gate * 64 + (u & 63);
#pragma unroll
    for (int r = 0; r < 8; ++r) {
        int i = rb + r;
        float v = acc[r];
        if (i < NU) v += W_r[(size_t)i * NG + col];
        Wzp[(size_t)qb * 512 * 256 + (size_t)i * 256 + lc] = v;
    }
}

// ---------------------------------------------------------------------------
// z_emb[m][n] = emb[inputs[m]] @ W_k[0:128] + b_lstm,  m = b*NT + t
// ---------------------------------------------------------------------------
__global__ __launch_bounds__(256) void zemb_kernel(
    const int* __restrict__ inputs, const float* __restrict__ emb,
    const float* __restrict__ W_k, const float* __restrict__ b_lstm,
    float* __restrict__ z_emb)
{
    const int col = blockIdx.x * 256 + threadIdx.x;
    const int m0 = blockIdx.y * 8;
    __shared__ float eS[8][NE];
    for (int i = threadIdx.x; i < 8 * NE; i += 256) {
        int r = i >> 7, e = i & 127;
        eS[r][e] = emb[(size_t)inputs[m0 + r] * NE + e];
    }
    __syncthreads();
    float acc[8] = {};
#pragma unroll 4
    for (int e = 0; e < NE; ++e) {
        float w = W_k[(size_t)e * NG + col];
#pragma unroll
        for (int r = 0; r < 8; ++r) acc[r] += eS[r][e] * w;
    }
    float bb = b_lstm[col];
#pragma unroll
    for (int r = 0; r < 8; ++r) z_emb[(size_t)(m0 + r) * NG + col] = acc[r] + bb;
}

// ---------------------------------------------------------------------------
// Cooperative recurrence: 256 blocks x 1024 threads (full chip).
// b = bid&63, u-slice qb = bid>>6; the 4 blocks of a batch share bid%8 ->
// same XCD under round-robin (perf heuristic; correctness is agent-scope).
// R5: 10 panel rows register-stationary per thread (P2 L2 traffic -31%),
// keys staged in LDS (P4 off L2), reduce widened to 256 threads.
// ---------------------------------------------------------------------------
constexpr int WS = 10;   // stationary panel rows per thread (40 VGPRs)

__global__ __launch_bounds__(1024, 4) void recurrence_coop(
    const float* __restrict__ z_emb,     // [NB*NT, NG] (includes bias)
    const float* __restrict__ sample_h,
    const float* __restrict__ sample_c,
    const float* __restrict__ Wzp,       // [4][512][256] panels
    const float* __restrict__ W_r,       // [NU, NG] raw (t==0 path)
    const float* __restrict__ memory,    // [NB, NS, NU]
    const float* __restrict__ keys,      // [NB, NS, NU]
    float* __restrict__ h_all,           // [NB*NT, NU] (also exchange buf)
    float* __restrict__ ctx_all,         // [NB*NT, NU]
    unsigned* __restrict__ bar)          // [NB] counters, pre-zeroed
{
    const int bid = blockIdx.x;
    const int b  = bid & 63;
    const int qb = bid >> 6;
    const int tid = threadIdx.x;

    __shared__ float memS[NS * NU];    // 31 KB
    __shared__ float keyS[NS * NU];    // 31 KB
    __shared__ float zPart[16 * 256];  // 16 KB
    __shared__ float zS[256];          // widened-reduce stage
    __shared__ float actS[2 * NU];     // [h | ctx]
    __shared__ float scS[32];

    const float* memb = memory + (size_t)b * NS * NU;
    const float* keyb = keys + (size_t)b * NS * NU;
    for (int i = tid; i < NS * NU / 4; i += 1024) {
        ((float4*)memS)[i] = ((const float4*)memb)[i];
        ((float4*)keyS)[i] = ((const float4*)keyb)[i];
    }
    if (tid < NU) actS[tid] = sample_h[b * NU + tid];
    float c_reg = (tid < 64) ? sample_c[b * NU + qb * 64 + tid] : 0.0f;

    const int colq = tid & 63;
    const int p    = tid >> 6;
    const int gate = colq >> 4, wq = colq & 15;
    const int ncol = gate * 256 + qb * 64 + wq * 4;
    const float* panel = Wzp + (size_t)qb * 512 * 256;
    const float* wp = panel + (size_t)(p * 32) * 256 + colq * 4;
    const float* zerow = z_emb + (size_t)(b * NT) * NG + ncol;
    unsigned* ctr = bar + b;

    // register-stationary panel rows k = 0..WS-1 of this thread's 32
    float4 wreg[WS];
#pragma unroll
    for (int k = 0; k < WS; ++k) wreg[k] = *(const float4*)(wp + (size_t)k * 256);

    __syncthreads();

    for (int t = 0; t < NT; ++t) {
        // --- P2: z-slice partials (split accumulators: stream || stationary)
        {
            float4 accr = (p == 0) ? *(const float4*)(zerow + (size_t)t * NG)
                                   : make_float4(0.f, 0.f, 0.f, 0.f);
            if (t == 0) {
                const float* ap = actS + p * 16;
#pragma unroll
                for (int k = 0; k < 16; ++k) {
                    float a = ap[k];
                    float4 w = *(const float4*)(W_r + (size_t)(p * 16 + k) * NG + ncol);
                    accr.x += a * w.x; accr.y += a * w.y;
                    accr.z += a * w.z; accr.w += a * w.w;
                }
                *(float4*)(zPart + p * 256 + colq * 4) = accr;
            } else {
                const float* ap = actS + p * 32;
                float4 accs = make_float4(0.f, 0.f, 0.f, 0.f);
#pragma unroll 11
                for (int k = WS; k < 32; ++k) {
                    float a = ap[k];
                    float4 w = *(const float4*)(wp + (size_t)k * 256);
                    accs.x += a * w.x; accs.y += a * w.y;
                    accs.z += a * w.z; accs.w += a * w.w;
                }
#pragma unroll
                for (int k = 0; k < WS; ++k) {
                    float a = ap[k];
                    accr.x += a * wreg[k].x; accr.y += a * wreg[k].y;
                    accr.z += a * wreg[k].z; accr.w += a * wreg[k].w;
                }
                accr.x += accs.x; accr.y += accs.y;
                accr.z += accs.z; accr.w += accs.w;
                *(float4*)(zPart + p * 256 + colq * 4) = accr;
            }
        }
        __syncthreads();

        // --- P3a: widened reduce (256 threads x 16 reads) ---
        if (tid < 256) {
            float s = 0.f;
#pragma unroll
            for (int q = 0; q < 16; ++q) s += zPart[q * 256 + tid];
            zS[tid] = s;
        }
        __syncthreads();

        // --- P3b: LSTM gates for own u-slice ---
        const size_t m = (size_t)b * NT + t;
        if (tid < 64) {
            float zi = zS[tid], zf = zS[64 + tid];
            float zg = zS[128 + tid], zo = zS[192 + tid];
            c_reg = sigmoidf_(zf) * c_reg + sigmoidf_(zi) * tanhf(zg);
            float h = sigmoidf_(zo) * tanhf(c_reg);
            __hip_atomic_store(h_all + m * NU + qb * 64 + tid, h,
                               __ATOMIC_RELAXED, __HIP_MEMORY_SCOPE_AGENT);
        }
        __syncthreads();   // drains vmcnt: h-slice stores complete before flag

        // --- 4-block barrier (monotonic counter, target 4*(t+1)) ---
        if (tid == 0) {
            __hip_atomic_fetch_add(ctr, 1u, __ATOMIC_RELAXED,
                                   __HIP_MEMORY_SCOPE_AGENT);
            const unsigned tgt = 4u * (unsigned)(t + 1);
            while (__hip_atomic_load(ctr, __ATOMIC_RELAXED,
                                     __HIP_MEMORY_SCOPE_AGENT) < tgt)
                __builtin_amdgcn_s_sleep(2);
        }
        __syncthreads();

        if (tid < NU)
            actS[tid] = __hip_atomic_load(h_all + m * NU + tid,
                                          __ATOMIC_RELAXED,
                                          __HIP_MEMORY_SCOPE_AGENT);
        __syncthreads();

        // --- P4: scores (keys from LDS now) ---
        {
            const int s = tid >> 5, j = tid & 31;
            if (s < NS) {
                float sp = 0.0f;
#pragma unroll
                for (int i = 0; i < 8; ++i)
                    sp += actS[i * 32 + j] * keyS[s * NU + i * 32 + j];
#pragma unroll
                for (int msk = 16; msk; msk >>= 1) sp += __shfl_xor(sp, msk, 32);
                if (j == 0) scS[s] = sp;
            }
        }
        __syncthreads();

        // --- P5: softmax + ctx ---
        if (tid < NU) {
            float mx = scS[0];
#pragma unroll
            for (int s = 1; s < NS; ++s) mx = fmaxf(mx, scS[s]);
            float sumE = 0.0f, ctx = 0.0f;
#pragma unroll 4
            for (int s = 0; s < NS; ++s) {
                float e = __expf(scS[s] - mx);
                sumE += e;
                ctx += e * memS[s * NU + tid];
            }
            ctx /= sumE;
            actS[NU + tid] = ctx;
            if (qb == 0) ctx_all[m * NU + tid] = ctx;
        }
        __syncthreads();
    }
}

// ---------------------------------------------------------------------------
// attn_all[m] = concat(h_all[m], ctx_all[m]) @ W_attn
// Also emits the bf16 split Ah/Al for the MFMA output GEMM.
// ---------------------------------------------------------------------------
__global__ __launch_bounds__(256) void attn_kernel(
    const float* __restrict__ h_all, const float* __restrict__ ctx_all,
    const float* __restrict__ W_a, float* __restrict__ attn_all,
    u16* __restrict__ Ahl)   // [2][NB*NT][NU]
{
    const int j = threadIdx.x;
    const int m0 = blockIdx.x * 8;
    __shared__ float hS[8][NU], cS[8][NU];
    for (int i = j; i < 8 * NU; i += 256) {
        int r = i >> 8, k = i & 255;
        hS[r][k] = h_all[(size_t)(m0 + r) * NU + k];
        cS[r][k] = ctx_all[(size_t)(m0 + r) * NU + k];
    }
    __syncthreads();
    float acc[8] = {};
#pragma unroll 2
    for (int k = 0; k < NU; ++k) {
        float w1 = W_a[(size_t)k * NU + j];
        float w2 = W_a[(size_t)(NU + k) * NU + j];
#pragma unroll
        for (int r = 0; r < 8; ++r) acc[r] += hS[r][k] * w1 + cS[r][k] * w2;
    }
#pragma unroll
    for (int r = 0; r < 8; ++r) {
        float a = acc[r];
        size_t m = (size_t)(m0 + r) * NU + j;
        attn_all[m] = a;
        u16 h = rne_bf16(a);
        float hf = __uint_as_float((unsigned)h << 16);
        Ahl[m] = h;
        Ahl[(size_t)NB * NT * NU + m] = rne_bf16(a - hf);
    }
}

// ---------------------------------------------------------------------------
// Pack W_fc [256][32000] f32 -> Bt [32000][512] bf16:  row n = [h(256)|l(256)]
// Single pass (reads W_fc once), dual LDS staging buffers.
// ---------------------------------------------------------------------------
__global__ __launch_bounds__(256) void wfc_pack(
    const float* __restrict__ Wfc, u16* __restrict__ Bt)
{
    const int n0 = blockIdx.x * 64;
    const int tid = threadIdx.x;
    __shared__ __align__(16) u16 tSh[64][264];
    __shared__ __align__(16) u16 tSl[64][264];

    for (int kk = 0; kk < 256; kk += 4) {
        int k = kk + (tid >> 6);
        int n = tid & 63;
        float v = Wfc[(size_t)k * NV + n0 + n];
        u16 h = rne_bf16(v);
        float hf = __uint_as_float((unsigned)h << 16);
        tSh[n][k] = h;
        tSl[n][k] = rne_bf16(v - hf);
    }
    __syncthreads();
    {
        int n = tid >> 2;
#pragma unroll
        for (int i = 0; i < 8; ++i) {
            int c = (tid & 3) + i * 4;   // 16B chunk index 0..31
            *(uint4*)(Bt + (size_t)(n0 + n) * 512 + c * 8) =
                *(const uint4*)(&tSh[n][c * 8]);
            *(uint4*)(Bt + (size_t)(n0 + n) * 512 + 256 + c * 8) =
                *(const uint4*)(&tSl[n][c * 8]);
        }
    }
}

// ---------------------------------------------------------------------------
// MFMA output GEMM: out = A @ W_fc + b, via split-bf16 3-term product.
// 128x128 tile, 4 waves (2x2) of 64x64, fragments straight from L2.
// R5: epilogue transposes C through LDS -> fully coalesced dwordx4 stores
// (was 64 scalar stride-NV stores per thread).
// ---------------------------------------------------------------------------
__global__ __launch_bounds__(256) void out_gemm_mfma(
    const u16* __restrict__ Ahl,    // [2][1920][256]
    const u16* __restrict__ Bt,     // [32000][512]
    const float* __restrict__ bfc,
    float* __restrict__ out)
{
    constexpr int NWG = (NV / 128) * ((NB * NT) / 128);  // 3750
    constexpr int qq = NWG / 8, rr = NWG % 8;            // 468, 6
    int bid = blockIdx.x;
    int xcd = bid & 7, idx = bid >> 3;
    int wg = (xcd < rr ? xcd * (qq + 1) : rr * (qq + 1) + (xcd - rr) * qq) + idx;
    const int nt = wg / 15, mt = wg % 15;   // m fastest within an XCD chunk
    const int n0 = nt * 128, m0 = mt * 128;

    const int tid = threadIdx.x;
    const int wave = tid >> 6, lane = tid & 63;
    const int wm = wave >> 1, wn = wave & 1;
    const int l15 = lane & 15, lq = lane >> 4;

    constexpr size_t ALOFF = (size_t)NB * NT * NU;  // Ah -> Al offset

    const u16* arow[4];
    const u16* brow[4];
#pragma unroll
    for (int f = 0; f < 4; ++f) {
        arow[f] = Ahl + (size_t)(m0 + wm * 64 + f * 16 + l15) * 256 + lq * 8;
        brow[f] = Bt + (size_t)(n0 + wn * 64 + f * 16 + l15) * 512 + lq * 8;
    }

    f32x4 acc[4][4] = {};

#pragma unroll
    for (int kk = 0; kk < 8; ++kk) {
        bf16x8 ah[4], al[4], bh[4], bl[4];
#pragma unroll
        for (int f = 0; f < 4; ++f) {
            ah[f] = *(const bf16x8*)(arow[f] + kk * 32);
            al[f] = *(const bf16x8*)(arow[f] + ALOFF + kk * 32);
            bh[f] = *(const bf16x8*)(brow[f] + kk * 32);
            bl[f] = *(const bf16x8*)(brow[f] + 256 + kk * 32);
        }
#pragma unroll
        for (int i = 0; i < 4; ++i)
#pragma unroll
            for (int j = 0; j < 4; ++j) {
                acc[i][j] = __builtin_amdgcn_mfma_f32_16x16x32_bf16(
                    ah[i], bh[j], acc[i][j], 0, 0, 0);
                acc[i][j] = __builtin_amdgcn_mfma_f32_16x16x32_bf16(
                    al[i], bh[j], acc[i][j], 0, 0, 0);
                acc[i][j] = __builtin_amdgcn_mfma_f32_16x16x32_bf16(
                    ah[i], bl[j], acc[i][j], 0, 0, 0);
            }
    }

    // ---- epilogue: transpose through LDS, coalesced dwordx4 stores ----
    __shared__ float cT[64][132];
    const int cq = tid & 31, r8 = tid >> 5;     // readback: 32 lanes = 1 row
    float4 bb = *(const float4*)(bfc + n0 + cq * 4);

#pragma unroll
    for (int hm = 0; hm < 2; ++hm) {
        if (wm == hm) {
#pragma unroll
            for (int i = 0; i < 4; ++i)
#pragma unroll
                for (int j = 0; j < 4; ++j)
#pragma unroll
                    for (int rg = 0; rg < 4; ++rg)
                        cT[i * 16 + lq * 4 + rg][wn * 64 + j * 16 + l15] =
                            acc[i][j][rg];
        }
        __syncthreads();
#pragma unroll
        for (int it = 0; it < 8; ++it) {
            int r = it * 8 + r8;
            float4 v = *(const float4*)&cT[r][cq * 4];
            v.x += bb.x; v.y += bb.y; v.z += bb.z; v.w += bb.w;
            *(float4*)(out + (size_t)(m0 + hm * 64 + r) * NV + n0 + cq * 4) = v;
        }
        __syncthreads();
    }
}

// ---------------------------------------------------------------------------
// Fallback fp32 out_gemm (used only if workspace too small for Bt).
// ---------------------------------------------------------------------------
constexpr int BM = 128, BN = 128, KC = 32, KTOT = NU;

__global__ __launch_bounds__(256) void out_gemm(
    const float* __restrict__ A,
    const float* __restrict__ Wfc,
    const float* __restrict__ bfc,
    float* __restrict__ out)
{
    const int n0 = blockIdx.x * BN;
    const int m0 = blockIdx.y * BM;
    const int tid = threadIdx.x;
    const int tx = tid & 15, ty = tid >> 4;

    __shared__ float As[KC][BM + 4];
    __shared__ float Bs[KC][BN];

    float acc[2][4][2][4] = {};

    const int kq = tid & 7,  r0 = tid >> 3;
    const int nq = tid & 31, kr0 = tid >> 5;

    float4 aR[4], bR[4];

#pragma unroll
    for (int p = 0; p < 4; ++p)
        aR[p] = *(const float4*)(A + (size_t)(m0 + r0 + p * 32) * KTOT + kq * 4);
#pragma unroll
    for (int p = 0; p < 4; ++p)
        bR[p] = *(const float4*)(Wfc + (size_t)(kr0 + p * 8) * NV + n0 + nq * 4);
#pragma unroll
    for (int p = 0; p < 4; ++p) {
        int r = r0 + p * 32;
        As[kq * 4 + 0][r] = aR[p].x;
        As[kq * 4 + 1][r] = aR[p].y;
        As[kq * 4 + 2][r] = aR[p].z;
        As[kq * 4 + 3][r] = aR[p].w;
        *(float4*)&Bs[kr0 + p * 8][nq * 4] = bR[p];
    }
    __syncthreads();

    for (int kb = 0; kb < KTOT; kb += KC) {
        const bool more = (kb + KC) < KTOT;
        if (more) {
#pragma unroll
            for (int p = 0; p < 4; ++p)
                aR[p] = *(const float4*)(A + (size_t)(m0 + r0 + p * 32) * KTOT + kb + KC + kq * 4);
#pragma unroll
            for (int p = 0; p < 4; ++p)
                bR[p] = *(const float4*)(Wfc + (size_t)(kb + KC + kr0 + p * 8) * NV + n0 + nq * 4);
        }

#pragma unroll 4
        for (int k = 0; k < KC; ++k) {
            float4 a0 = *(const float4*)&As[k][ty * 4];
            float4 a1 = *(const float4*)&As[k][64 + ty * 4];
            float4 b0 = *(const float4*)&Bs[k][tx * 4];
            float4 b1 = *(const float4*)&Bs[k][64 + tx * 4];
            float am[2][4] = {{a0.x, a0.y, a0.z, a0.w}, {a1.x, a1.y, a1.z, a1.w}};
            float bv[2][4] = {{b0.x, b0.y, b0.z, b0.w}, {b1.x, b1.y, b1.z, b1.w}};
#pragma unroll
            for (int im = 0; im < 2; ++im)
#pragma unroll
                for (int i = 0; i < 4; ++i)
#pragma unroll
                    for (int jn = 0; jn < 2; ++jn)
#pragma unroll
                        for (int j = 0; j < 4; ++j)
                            acc[im][i][jn][j] += am[im][i] * bv[jn][j];
        }
        __syncthreads();

        if (more) {
#pragma unroll
            for (int p = 0; p < 4; ++p) {
                int r = r0 + p * 32;
                As[kq * 4 + 0][r] = aR[p].x;
                As[kq * 4 + 1][r] = aR[p].y;
                As[kq * 4 + 2][r] = aR[p].z;
                As[kq * 4 + 3][r] = aR[p].w;
                *(float4*)&Bs[kr0 + p * 8][nq * 4] = bR[p];
            }
            __syncthreads();
        }
    }

    float4 bias[2];
    bias[0] = *(const float4*)(bfc + n0 + tx * 4);
    bias[1] = *(const float4*)(bfc + n0 + 64 + tx * 4);
#pragma unroll
    for (int im = 0; im < 2; ++im)
#pragma unroll
        for (int i = 0; i < 4; ++i) {
            int m = m0 + im * 64 + ty * 4 + i;
#pragma unroll
            for (int jn = 0; jn < 2; ++jn) {
                float4 v;
                float4 bb = bias[jn];
                v.x = acc[im][i][jn][0] + bb.x;
                v.y = acc[im][i][jn][1] + bb.y;
                v.z = acc[im][i][jn][2] + bb.z;
                v.w = acc[im][i][jn][3] + bb.w;
                *(float4*)(out + (size_t)m * NV + n0 + jn * 64 + tx * 4) = v;
            }
        }
}

// ---------------------------------------------------------------------------
extern "C" void kernel_launch(void* const* d_in, const int* in_sizes, int n_in,
                              void* d_out, int out_size, void* d_ws, size_t ws_size,
                              hipStream_t stream) {
    const int*   inputs   = (const int*)  d_in[0];
    const float* memory   = (const float*)d_in[1];
    const float* sample_h = (const float*)d_in[2];
    const float* sample_c = (const float*)d_in[3];
    const float* emb      = (const float*)d_in[4];
    const float* W_k      = (const float*)d_in[5];
    const float* W_r      = (const float*)d_in[6];
    const float* b_lstm   = (const float*)d_in[7];
    const float* W_mem    = (const float*)d_in[8];
    const float* W_attn   = (const float*)d_in[9];
    const float* W_fc     = (const float*)d_in[10];
    const float* b_fc     = (const float*)d_in[11];
    float* out = (float*)d_out;

    // workspace layout (float units)
    constexpr size_t SZ_KEYS = (size_t)NB * NS * NU;        // 507,904
    constexpr size_t SZ_WZ   = (size_t)4 * 512 * 256;       // 524,288
    constexpr size_t SZ_ZEMB = (size_t)NB * NT * NG;        // 1,966,080
    constexpr size_t SZ_ACT  = (size_t)NB * NT * NU;        // 491,520
    constexpr size_t SZ_AHL  = SZ_ACT;                      // 2x bf16 = 1x f32
    constexpr size_t SZ_BAR  = 64;
    constexpr size_t SZ_BT   = (size_t)NV * 512 / 2;        // 8,192,000

    float* keys     = (float*)d_ws;
    float* Wzp      = keys + SZ_KEYS;
    float* z_emb    = Wzp + SZ_WZ;
    float* h_all    = z_emb + SZ_ZEMB;
    float* ctx_all  = h_all + SZ_ACT;
    float* attn_all = ctx_all + SZ_ACT;
    u16*   Ahl      = (u16*)(attn_all + SZ_ACT);
    unsigned* bar   = (unsigned*)(attn_all + SZ_ACT + SZ_AHL);
    float* bt_f     = attn_all + SZ_ACT + SZ_AHL + SZ_BAR;
    u16*   Bt       = (u16*)bt_f;

    const size_t need_bytes =
        (SZ_KEYS + SZ_WZ + SZ_ZEMB + 3 * SZ_ACT + SZ_AHL + SZ_BAR + SZ_BT) * 4;
    const bool use_mfma = ws_size >= need_bytes;

    keys_kernel<<<(NB * NS) / 8, 256, 0, stream>>>(memory, W_mem, keys);
    fuse_wz_kernel<<<dim3(NG / 256, (2 * NU) / 8), 256, 0, stream>>>(W_k, W_r,
                                                                     W_attn, Wzp);
    zemb_kernel<<<dim3(NG / 256, (NB * NT) / 8), 256, 0, stream>>>(inputs, emb,
                                                                   W_k, b_lstm,
                                                                   z_emb);
    if (use_mfma)
        wfc_pack<<<NV / 64, 256, 0, stream>>>(W_fc, Bt);

    hipMemsetAsync(bar, 0, NB * sizeof(unsigned), stream);

    {
        void* kargs[] = {
            (void*)&z_emb, (void*)&sample_h, (void*)&sample_c, (void*)&Wzp,
            (void*)&W_r, (void*)&memory, (void*)&keys, (void*)&h_all,
            (void*)&ctx_all, (void*)&bar
        };
        hipLaunchCooperativeKernel((const void*)recurrence_coop,
                                   dim3(NB * 4), dim3(1024), kargs, 0, stream);
    }

    attn_kernel<<<(NB * NT) / 8, 256, 0, stream>>>(h_all, ctx_all, W_attn,
                                                   attn_all, Ahl);

    if (use_mfma) {
        out_gemm_mfma<<<(NV / 128) * ((NB * NT) / 128), 256, 0, stream>>>(
            Ahl, Bt, b_fc, out);
    } else {
        out_gemm<<<dim3(NV / BN, (NB * NT) / BM), 256, 0, stream>>>(
            attn_all, W_fc, b_fc, out);
    }
}